// Round 10
// baseline (2375.132 us; speedup 1.0000x reference)
//
#include <hip/hip_runtime.h>
#include <hip/hip_bf16.h>
#include <math.h>

typedef float f32x4 __attribute__((ext_vector_type(4)));
typedef float f32x2 __attribute__((ext_vector_type(2)));
typedef short s16x8 __attribute__((ext_vector_type(8)));

// ---- workspace layout (bytes) ---- total < 1 MB
static const long long OFF_W2  = 0LL;        // bf16 [9][128][64]  = 147,456 B
static const long long OFF_W3  = 147456LL;   // bf16 [9][256][128] = 589,824 B
static const long long OFF_AB1 = 737280LL;   // float2 [64]
static const long long OFF_AB2 = 737792LL;   // float2 [128]
static const long long OFF_AB3 = 738816LL;   // float2 [256]
static const long long OFF_Q   = 740864LL;   // float  [8]: A0,A1,C0,C1,cos(qp1),fc1b1

__device__ inline unsigned short f2bfu(float f) {
    __hip_bfloat16 h = __float2bfloat16(f);
    unsigned short u;
    __builtin_memcpy(&u, &h, 2);
    return u;
}

// ---------------- prep: weight transpose to [kykx][oc][ic] bf16 + BN folding + fc fold ----------------
__global__ __launch_bounds__(256) void prep_k(
    const float* __restrict__ c2w, const float* __restrict__ c3w,
    const float* __restrict__ c1b, const float* __restrict__ g1, const float* __restrict__ b1,
    const float* __restrict__ m1, const float* __restrict__ v1,
    const float* __restrict__ c2b, const float* __restrict__ g2, const float* __restrict__ b2,
    const float* __restrict__ m2, const float* __restrict__ v2,
    const float* __restrict__ c3b, const float* __restrict__ g3, const float* __restrict__ b3,
    const float* __restrict__ m3, const float* __restrict__ v3,
    const float* __restrict__ fc1b, const float* __restrict__ qp,
    const float* __restrict__ fc2w, const float* __restrict__ fc2b,
    const float* __restrict__ fc3w, const float* __restrict__ fc3b,
    short* __restrict__ wT2, short* __restrict__ wT3,
    float2* __restrict__ ab1, float2* __restrict__ ab2, float2* __restrict__ ab3,
    float* __restrict__ qc)
{
    int tid = blockIdx.x * 256 + threadIdx.x;
    if (tid < 73728) {                       // 9*128*64
        int ic = tid & 63, oc = (tid >> 6) & 127, k = tid >> 13;
        wT2[tid] = (short)f2bfu(c2w[(oc * 64 + ic) * 9 + k]);
    }
    if (tid < 294912) {                      // 9*256*128
        int ic = tid & 127, oc = (tid >> 7) & 255, k = tid >> 15;
        wT3[tid] = (short)f2bfu(c3w[(oc * 128 + ic) * 9 + k]);
    }
    if (tid < 64) {
        float s = g1[tid] / sqrtf(v1[tid] + 1e-5f);
        ab1[tid] = make_float2(s, (c1b[tid] - m1[tid]) * s + b1[tid]);
    } else if (tid < 192) {
        int c = tid - 64;
        float s = g2[c] / sqrtf(v2[c] + 1e-5f);
        ab2[c] = make_float2(s, (c2b[c] - m2[c]) * s + b2[c]);
    } else if (tid < 448) {
        int c = tid - 192;
        float s = g3[c] / sqrtf(v3[c] + 1e-5f);
        ab3[c] = make_float2(s, (c3b[c] - m3[c]) * s + b3[c]);
    } else if (tid == 448) {
        float A0 = 0.f, A1 = 0.f, B0 = 0.f, B1 = 0.f;
        for (int k = 0; k < 128; ++k) {
            float f2 = fc2w[k], fb = fc2b[k];
            A0 += fc3w[k] * f2;        B0 += fc3w[k] * fb;
            A1 += fc3w[128 + k] * f2;  B1 += fc3w[128 + k] * fb;
        }
        qc[0] = A0; qc[1] = A1;
        qc[2] = B0 + fc3b[0]; qc[3] = B1 + fc3b[1];
        qc[4] = cosf(qp[1]);  qc[5] = fc1b[1];
    }
}

// ---------------- fused: LDS-port-minimized version (RESUBMIT of R9 — infra failure, no data) ----
// THEORY (R8 post-mortem): per-CU LDS port (~112 B/cyc) is the binding resource at 3 blocks/CU.
// conv2's 8 waves previously each re-read the same B tiles (8x duplication) = 64% of port time.
// This version:
//  - conv2: wave = (oc-pair g2i, pos-half h2); each B ds_read_b128 feeds 2 MFMAs. Two passes
//    (4 nt then 3 nt) keep acc at 32 regs so total stays under the 85-reg 3-block budget.
//  - conv3: wave = (oc-quad q3, pos-split h3: nt{0,1}/{2}); each B read feeds 4 MFMAs.
//  - 48 KB LDS union (R4) + strength-reduced addressing (R6) + (512,6) for 3 blocks/CU.
// Port/block: ~25K cyc (R4) -> ~17K cyc; at 3 blocks: 75K -> 52K per CU slot.
__global__ __launch_bounds__(512, 6) void fused_k(
    const float* __restrict__ x, const float* __restrict__ c1w,
    const float2* __restrict__ ab1, const float2* __restrict__ ab2,
    const float2* __restrict__ ab3,
    const short* __restrict__ wT2, const short* __restrict__ wT3,
    const float* __restrict__ fc1w, const float* __restrict__ qc,
    float* __restrict__ out)
{
    __shared__ short xs2[16 * 16 * 64];      // conv2 input tile [y][x][8 blk][8 ic], swizzled (32 KB)
    __shared__ short u3[8 * 8 * 128];        // 16 KB UNION: stage-A xt / conv3 xs3 / final red

    float (*xt)[32] = (float (*)[32])u3;     // padded 28x28 input at [1..28][1..28]
    short* xs3 = u3;                         // conv3 input tile [y][x][16 blk][8 ic], swizzled
    float* red = (float*)u3;                 // 8 floats, valid after post-conv3 barrier

    int b = blockIdx.x, t = threadIdx.x;

    // ---- zero-init ----
    for (int i = t; i < 8192; i += 512) ((unsigned*)xs2)[i] = 0u;
    for (int i = t; i < 960;  i += 512) ((unsigned*)u3)[i] = 0u;
    __syncthreads();

    // ---- stage A: conv1 (VALU fp32, f32x2) + BN + ReLU + pool -> xs2 ----
    for (int i = t; i < 784; i += 512) xt[i / 28 + 1][i % 28 + 1] = x[b * 784 + i];

    int ocg = t & 15;
    float wr[4][9];
    float2 abr[4];
#pragma unroll
    for (int c = 0; c < 4; ++c) {
#pragma unroll
        for (int k = 0; k < 9; ++k) wr[c][k] = c1w[(ocg * 4 + c) * 9 + k];
        abr[c] = ab1[ocg * 4 + c];
    }
    __syncthreads();

    int posb = t >> 4;
    for (int p = posb; p < 196; p += 32) {
        int py = p / 14, px = p % 14;
        int y0 = 2 * py, x0 = 2 * px;
        float patch[4][4];
#pragma unroll
        for (int i = 0; i < 4; ++i)
#pragma unroll
            for (int j = 0; j < 4; ++j) patch[i][j] = xt[y0 + i][x0 + j];

        unsigned short ub[4];
#pragma unroll
        for (int c = 0; c < 4; ++c) {
            f32x2 r0 = {0.f, 0.f};
            f32x2 r1 = {0.f, 0.f};
#pragma unroll
            for (int ky = 0; ky < 3; ++ky)
#pragma unroll
                for (int kx = 0; kx < 3; ++kx) {
                    float wv = wr[c][ky * 3 + kx];
                    f32x2 p0 = {patch[ky + 0][kx], patch[ky + 0][kx + 1]};
                    f32x2 p1 = {patch[ky + 1][kx], patch[ky + 1][kx + 1]};
                    r0 += p0 * wv;
                    r1 += p1 * wv;
                }
            float aa = abr[c].x, bb = abr[c].y;
            f32x2 s0 = r0 * aa + bb;
            f32x2 s1 = r1 * aa + bb;
            float v = fmaxf(fmaxf(s0.x, s0.y), fmaxf(s1.x, s1.y));
            ub[c] = f2bfu(fmaxf(v, 0.f));
        }
        uint2 pk;
        pk.x = (unsigned)ub[0] | ((unsigned)ub[1] << 16);
        pk.y = (unsigned)ub[2] | ((unsigned)ub[3] << 16);
        int blk = (ocg >> 1) ^ ((px + 1) & 7);
        *(uint2*)&xs2[((((py + 1) * 16) + (px + 1)) * 8 + blk) * 8 + (ocg & 1) * 4] = pk;
    }
    __syncthreads();
    // xt dead; u3 becomes xs3. Zero the halo (row 0, col 0) only.
    for (int i = t; i < 960; i += 512) {
        int pos = i >> 6, w = i & 63;
        int yy = (pos < 8) ? 0 : pos - 7;
        int xx = (pos < 8) ? pos : 0;
        ((unsigned*)xs3)[(yy * 8 + xx) * 64 + w] = 0u;
    }

    // ---- stage B: conv2 (64->128), oc-paired, two position passes ----
    int lane = t & 63, wid = t >> 6;
    int quad = lane >> 4, n16 = lane & 15;
    int dy = n16 >> 3, lx = n16 & 7;

    {
        int g2i = wid & 3;                   // oc-pair group: oc g2i*32 .. g2i*32+31
        int h2  = wid >> 2;                  // position half: nt = h2*7 .. h2*7+6

        int boff[7];                         // ry*2048 shorts per local idx (const-indexed -> regs)
#pragma unroll
        for (int idx = 0; idx < 7; ++idx) boff[idx] = ((h2 * 7 + idx) >> 1) * 2048;

        const short* pA_base = wT2 + (g2i * 32 + n16) * 64 + quad * 8;   // tile1 at +1024 shorts

        int m = lx >> 1;
        bool keep = (dy == 0) && ((lx & 1) == 0);

#pragma unroll
        for (int p = 0; p < 2; ++p) {
            const int NI = p ? 3 : 4;        // pass 0: idx 0..3, pass 1: idx 4..6
            f32x4 acc0[4], acc1[4];
            f32x4 z = {0.f, 0.f, 0.f, 0.f};
#pragma unroll
            for (int i = 0; i < 4; ++i) { acc0[i] = z; acc1[i] = z; }

#pragma unroll 1
            for (int kykx = 0; kykx < 9; ++kykx) {
                int ky = kykx / 3, kx = kykx - 3 * ky;
                int dyky = dy + ky;
                int xc0 = lx + kx;
                int xc1 = xc0 + 8; if (xc1 > 15) xc1 = 15;   // lanes lx>=6 discarded later
                const short* pA = pA_base + kykx * 8192;
#pragma unroll
                for (int kk = 0; kk < 2; ++kk) {
                    s16x8 A0 = *(const s16x8*)(pA + kk * 32);
                    s16x8 A1 = *(const s16x8*)(pA + kk * 32 + 1024);
                    int bi = kk * 4 + quad;
                    const short* pB0 = &xs2[((dyky * 16 + xc0) * 8 + (bi ^ (xc0 & 7))) * 8];
                    const short* pB1 = &xs2[((dyky * 16 + xc1) * 8 + (bi ^ (xc1 & 7))) * 8];
                    // idx parity: cb = (h2*7+idx)&1 = h2 ^ (idx&1); idx = p*4+i -> parity = i&1
                    const short* pEven = h2 ? pB1 : pB0;
                    const short* pOdd  = h2 ? pB0 : pB1;
#pragma unroll
                    for (int i = 0; i < 4; ++i) {
                        if (i < NI) {
                            int idx = p * 4 + i;
                            const short* pb = ((i & 1) == 0) ? pEven : pOdd;
                            s16x8 B = *(const s16x8*)(pb + boff[idx]);
                            acc0[i] = __builtin_amdgcn_mfma_f32_16x16x32_bf16(A0, B, acc0[i], 0, 0, 0);
                            acc1[i] = __builtin_amdgcn_mfma_f32_16x16x32_bf16(A1, B, acc1[i], 0, 0, 0);
                        }
                    }
                }
            }

            // epilogue for this pass: affine -> pool (shfl 1,8) -> ReLU -> xs3 (swizzled)
#pragma unroll
            for (int ml = 0; ml < 2; ++ml) {
                int oc0 = g2i * 32 + ml * 16 + quad * 4;
                float2 abv[4];
#pragma unroll
                for (int r = 0; r < 4; ++r) abv[r] = ab2[oc0 + r];
#pragma unroll
                for (int i = 0; i < 4; ++i) {
                    if (i < NI) {
                        int nt = h2 * 7 + p * 4 + i;
                        int ry = nt >> 1, cb = nt & 1;
                        int xp = cb * 4 + m;
                        float pv[4];
#pragma unroll
                        for (int r = 0; r < 4; ++r) {
                            float v = (ml ? acc1[i][r] : acc0[i][r]) * abv[r].x + abv[r].y;
                            v = fmaxf(v, __shfl_xor(v, 1));
                            v = fmaxf(v, __shfl_xor(v, 8));
                            pv[r] = fmaxf(v, 0.f);
                        }
                        if (keep && xp < 7) {
                            uint2 pk;
                            pk.x = (unsigned)f2bfu(pv[0]) | ((unsigned)f2bfu(pv[1]) << 16);
                            pk.y = (unsigned)f2bfu(pv[2]) | ((unsigned)f2bfu(pv[3]) << 16);
                            int blk3 = (oc0 >> 3) ^ (((xp + 1) & 7) << 1);
                            *(uint2*)&xs3[(((ry + 1) * 8 + (xp + 1)) * 16 + blk3) * 8 + (oc0 & 7)] = pk;
                        }
                    }
                }
            }
        }
    }
    __syncthreads();

    // ---- stage C: conv3 (128->256), 4-way oc-shared B, pos split 2/1 ----
    {
        int q3 = wid & 3;                    // oc-quad: tiles q3*4 .. q3*4+3 (oc q3*64 .. +63)
        int h3 = wid >> 2;                   // 0: nt {0,1}; 1: nt {2}

        f32x4 c3a[4][2];
        f32x4 z = {0.f, 0.f, 0.f, 0.f};
#pragma unroll
        for (int ml = 0; ml < 4; ++ml)
#pragma unroll
            for (int j = 0; j < 2; ++j) c3a[ml][j] = z;

        int boff3[2];
#pragma unroll
        for (int j = 0; j < 2; ++j) boff3[j] = (h3 * 2 + j) * 2048;   // nt*2048 shorts

        const short* pW_base = wT3 + (q3 * 64 + n16) * 128 + quad * 8;  // ml at +ml*2048 shorts

#pragma unroll 1
        for (int kykx = 0; kykx < 9; ++kykx) {
            int ky = kykx / 3, kx = kykx - 3 * ky;
            int dyky = dy + ky;
            int x_in = lx + kx; if (x_in > 7) x_in = 7;   // lanes lx>=6 discarded later
            const short* pW = pW_base + kykx * 32768;
#pragma unroll
            for (int kk = 0; kk < 4; ++kk) {
                s16x8 A0 = *(const s16x8*)(pW + kk * 32);
                s16x8 A1 = *(const s16x8*)(pW + kk * 32 + 2048);
                s16x8 A2 = *(const s16x8*)(pW + kk * 32 + 4096);
                s16x8 A3 = *(const s16x8*)(pW + kk * 32 + 6144);
                int bi = kk * 4 + quad;
                int blk = bi ^ ((x_in & 7) << 1);
                const short* pB = &xs3[((dyky * 8 + x_in) * 16 + blk) * 8];
#pragma unroll
                for (int j = 0; j < 2; ++j) {
                    if (j == 0 || h3 == 0) {             // h3=1 only does j=0 (nt=2)
                        s16x8 B = *(const s16x8*)(pB + boff3[j]);
                        c3a[0][j] = __builtin_amdgcn_mfma_f32_16x16x32_bf16(A0, B, c3a[0][j], 0, 0, 0);
                        c3a[1][j] = __builtin_amdgcn_mfma_f32_16x16x32_bf16(A1, B, c3a[1][j], 0, 0, 0);
                        c3a[2][j] = __builtin_amdgcn_mfma_f32_16x16x32_bf16(A2, B, c3a[2][j], 0, 0, 0);
                        c3a[3][j] = __builtin_amdgcn_mfma_f32_16x16x32_bf16(A3, B, c3a[3][j], 0, 0, 0);
                    }
                }
            }
        }
        __syncthreads();                     // all xs3 reads done -> u3 reusable as red

        // epilogue: affine -> pool -> relu -> dot with fc1_w row 1
        float vacc = 0.f;
        int m = lx >> 1;
        bool keep = (dy == 0) && ((lx & 1) == 0) && (m < 3);
        const float* fc1w1 = fc1w + 2304;
#pragma unroll
        for (int ml = 0; ml < 4; ++ml) {
            int oc0 = (q3 * 4 + ml) * 16 + quad * 4;
            float2 abv[4];
#pragma unroll
            for (int r = 0; r < 4; ++r) abv[r] = ab3[oc0 + r];
#pragma unroll
            for (int j = 0; j < 2; ++j) {
                if (j == 0 || h3 == 0) {
                    int nt = h3 * 2 + j;
#pragma unroll
                    for (int r = 0; r < 4; ++r) {
                        float v = c3a[ml][j][r] * abv[r].x + abv[r].y;
                        v = fmaxf(v, __shfl_xor(v, 1));
                        v = fmaxf(v, __shfl_xor(v, 8));
                        v = fmaxf(v, 0.f);
                        if (keep) vacc += v * fc1w1[(oc0 + r) * 9 + nt * 3 + m];
                    }
                }
            }
        }
#pragma unroll
        for (int s = 1; s < 64; s <<= 1) vacc += __shfl_xor(vacc, s);
        if (lane == 0) red[wid] = vacc;
    }
    __syncthreads();
    if (t == 0) {
        float v = red[0] + red[1] + red[2] + red[3]
                + red[4] + red[5] + red[6] + red[7] + qc[5];
        float q = cosf(v) * qc[4];
        float l0 = q * qc[0] + qc[2];
        float l1 = q * qc[1] + qc[3];
        float mx = fmaxf(l0, l1);
        float lse = mx + logf(__expf(l0 - mx) + __expf(l1 - mx));
        out[b * 2 + 0] = l0 - lse;
        out[b * 2 + 1] = l1 - lse;
    }
}

extern "C" void kernel_launch(void* const* d_in, const int* in_sizes, int n_in,
                              void* d_out, int out_size, void* d_ws, size_t ws_size,
                              hipStream_t stream)
{
    const float* x    = (const float*)d_in[0];
    const float* c1w  = (const float*)d_in[1];
    const float* c1b  = (const float*)d_in[2];
    const float* c2w  = (const float*)d_in[3];
    const float* c2b  = (const float*)d_in[4];
    const float* c3w  = (const float*)d_in[5];
    const float* c3b  = (const float*)d_in[6];
    const float* g1   = (const float*)d_in[7];
    const float* b1   = (const float*)d_in[8];
    const float* m1   = (const float*)d_in[9];
    const float* v1   = (const float*)d_in[10];
    const float* g2   = (const float*)d_in[11];
    const float* b2   = (const float*)d_in[12];
    const float* m2   = (const float*)d_in[13];
    const float* v2   = (const float*)d_in[14];
    const float* g3   = (const float*)d_in[15];
    const float* b3   = (const float*)d_in[16];
    const float* m3   = (const float*)d_in[17];
    const float* v3   = (const float*)d_in[18];
    const float* fc1w = (const float*)d_in[19];
    const float* fc1b = (const float*)d_in[20];
    const float* qp   = (const float*)d_in[21];
    const float* fc2w = (const float*)d_in[22];
    const float* fc2b = (const float*)d_in[23];
    const float* fc3w = (const float*)d_in[24];
    const float* fc3b = (const float*)d_in[25];
    float* out = (float*)d_out;
    char* ws = (char*)d_ws;

    short*  wT2 = (short*)(ws + OFF_W2);
    short*  wT3 = (short*)(ws + OFF_W3);
    float2* ab1 = (float2*)(ws + OFF_AB1);
    float2* ab2 = (float2*)(ws + OFF_AB2);
    float2* ab3 = (float2*)(ws + OFF_AB3);
    float*  qc  = (float*)(ws + OFF_Q);

    int B = in_sizes[0] / 784;               // 8192

    prep_k<<<1152, 256, 0, stream>>>(c2w, c3w, c1b, g1, b1, m1, v1,
                                     c2b, g2, b2, m2, v2, c3b, g3, b3, m3, v3,
                                     fc1b, qp, fc2w, fc2b, fc3w, fc3b,
                                     wT2, wT3, ab1, ab2, ab3, qc);
    fused_k<<<B, 512, 0, stream>>>(x, c1w, ab1, ab2, ab3, wT2, wT3, fc1w, qc, out);
}

// Round 11
// 1003.622 us; speedup vs baseline: 2.3666x; 2.3666x over previous
//
#include <hip/hip_runtime.h>
#include <hip/hip_bf16.h>
#include <math.h>

typedef float f32x4 __attribute__((ext_vector_type(4)));
typedef short s16x8 __attribute__((ext_vector_type(8)));

// ---- workspace layout (bytes) ---- total < 1 MB
static const long long OFF_W2  = 0LL;        // bf16 [9][128][64]  = 147,456 B
static const long long OFF_W3  = 147456LL;   // bf16 [9][256][128] = 589,824 B
static const long long OFF_AB1 = 737280LL;   // float2 [64]
static const long long OFF_AB2 = 737792LL;   // float2 [128]
static const long long OFF_AB3 = 738816LL;   // float2 [256]
static const long long OFF_Q   = 740864LL;   // float  [8]: A0,A1,C0,C1,cos(qp1),fc1b1

__device__ inline unsigned short f2bfu(float f) {
    __hip_bfloat16 h = __float2bfloat16(f);
    unsigned short u;
    __builtin_memcpy(&u, &h, 2);
    return u;
}

// ---------------- prep: weight transpose to [kykx][oc][ic] bf16 + BN folding + fc fold ----------------
__global__ __launch_bounds__(256) void prep_k(
    const float* __restrict__ c2w, const float* __restrict__ c3w,
    const float* __restrict__ c1b, const float* __restrict__ g1, const float* __restrict__ b1,
    const float* __restrict__ m1, const float* __restrict__ v1,
    const float* __restrict__ c2b, const float* __restrict__ g2, const float* __restrict__ b2,
    const float* __restrict__ m2, const float* __restrict__ v2,
    const float* __restrict__ c3b, const float* __restrict__ g3, const float* __restrict__ b3,
    const float* __restrict__ m3, const float* __restrict__ v3,
    const float* __restrict__ fc1b, const float* __restrict__ qp,
    const float* __restrict__ fc2w, const float* __restrict__ fc2b,
    const float* __restrict__ fc3w, const float* __restrict__ fc3b,
    short* __restrict__ wT2, short* __restrict__ wT3,
    float2* __restrict__ ab1, float2* __restrict__ ab2, float2* __restrict__ ab3,
    float* __restrict__ qc)
{
    int tid = blockIdx.x * 256 + threadIdx.x;
    if (tid < 73728) {                       // 9*128*64
        int ic = tid & 63, oc = (tid >> 6) & 127, k = tid >> 13;
        wT2[tid] = (short)f2bfu(c2w[(oc * 64 + ic) * 9 + k]);
    }
    if (tid < 294912) {                      // 9*256*128
        int ic = tid & 127, oc = (tid >> 7) & 255, k = tid >> 15;
        wT3[tid] = (short)f2bfu(c3w[(oc * 128 + ic) * 9 + k]);
    }
    if (tid < 64) {
        float s = g1[tid] / sqrtf(v1[tid] + 1e-5f);
        ab1[tid] = make_float2(s, (c1b[tid] - m1[tid]) * s + b1[tid]);
    } else if (tid < 192) {
        int c = tid - 64;
        float s = g2[c] / sqrtf(v2[c] + 1e-5f);
        ab2[c] = make_float2(s, (c2b[c] - m2[c]) * s + b2[c]);
    } else if (tid < 448) {
        int c = tid - 192;
        float s = g3[c] / sqrtf(v3[c] + 1e-5f);
        ab3[c] = make_float2(s, (c3b[c] - m3[c]) * s + b3[c]);
    } else if (tid == 448) {
        float A0 = 0.f, A1 = 0.f, B0 = 0.f, B1 = 0.f;
        for (int k = 0; k < 128; ++k) {
            float f2 = fc2w[k], fb = fc2b[k];
            A0 += fc3w[k] * f2;        B0 += fc3w[k] * fb;
            A1 += fc3w[128 + k] * f2;  B1 += fc3w[128 + k] * fb;
        }
        qc[0] = A0; qc[1] = A1;
        qc[2] = B0 + fc3b[0]; qc[3] = B1 + fc3b[1];
        qc[4] = cosf(qp[1]);  qc[5] = fc1b[1];
    }
}

// ---------------- fused: R4-despill ----------------
// EXACT R4 skeleton (48 KB LDS union, (512,6) -> 3 blocks/CU = 24 waves, 935us best) with ONE
// change: conv2 runs as TWO sequential passes of 7 nt-tiles (acc[7] = 28 AGPR) instead of one
// pass of 14 (acc[14] = 56 AGPR). Peak reg demand drops below the 85-reg 6-wave cap, removing
// R4's 177 MB scratch spill. Cost: conv2 kykx/A-load loop runs twice (A global re-loads, L2-hot).
// LDS B-read volume unchanged. Single-variable test: spill tax vs 3-block port wall.
__global__ __launch_bounds__(512, 6) void fused_k(
    const float* __restrict__ x, const float* __restrict__ c1w,
    const float2* __restrict__ ab1, const float2* __restrict__ ab2,
    const float2* __restrict__ ab3,
    const short* __restrict__ wT2, const short* __restrict__ wT3,
    const float* __restrict__ fc1w, const float* __restrict__ qc,
    float* __restrict__ out)
{
    __shared__ short xs2[16 * 16 * 64];      // conv2 input tile [y][x][8 blk][8 ic], swizzled (32 KB)
    __shared__ short u3[8 * 8 * 128];        // 16 KB UNION: stage-A xt / conv3 xs3 / final red

    float (*xt)[32] = (float (*)[32])u3;     // padded 28x28 input at [1..28][1..28]
    short* xs3 = u3;                         // conv3 input tile [y][x][16 blk][8 ic], swizzled
    float* red = (float*)u3;                 // 8 floats, valid only after post-conv3 barrier

    int b = blockIdx.x, t = threadIdx.x;

    // ---- zero-init (xs2 fully; xt incl. borders) ----
    for (int i = t; i < 8192; i += 512) ((unsigned*)xs2)[i] = 0u;
    for (int i = t; i < 960;  i += 512) ((unsigned*)u3)[i] = 0u;
    __syncthreads();

    // ---- stage A: load input, conv1 (VALU fp32) + BN + ReLU + 2x2 pool -> xs2 ----
    for (int i = t; i < 784; i += 512) xt[i / 28 + 1][i % 28 + 1] = x[b * 784 + i];

    int ocg = t & 15;                        // 16 groups of 4 output channels
    float wr[4][9];
    float2 abr[4];
#pragma unroll
    for (int c = 0; c < 4; ++c) {
#pragma unroll
        for (int k = 0; k < 9; ++k) wr[c][k] = c1w[(ocg * 4 + c) * 9 + k];
        abr[c] = ab1[ocg * 4 + c];
    }
    __syncthreads();

    int posb = t >> 4;                       // 0..31
    for (int p = posb; p < 196; p += 32) {
        int py = p / 14, px = p % 14;
        int y0 = 2 * py, x0 = 2 * px;
        float patch[4][4];
#pragma unroll
        for (int i = 0; i < 4; ++i)
#pragma unroll
            for (int j = 0; j < 4; ++j) patch[i][j] = xt[y0 + i][x0 + j];

        unsigned short ub[4];
#pragma unroll
        for (int c = 0; c < 4; ++c) {
            float a00 = 0.f, a01 = 0.f, a10 = 0.f, a11 = 0.f;
#pragma unroll
            for (int ky = 0; ky < 3; ++ky)
#pragma unroll
                for (int kx = 0; kx < 3; ++kx) {
                    float wv = wr[c][ky * 3 + kx];
                    a00 += patch[ky + 0][kx + 0] * wv;
                    a01 += patch[ky + 0][kx + 1] * wv;
                    a10 += patch[ky + 1][kx + 0] * wv;
                    a11 += patch[ky + 1][kx + 1] * wv;
                }
            float aa = abr[c].x, bb = abr[c].y;
            float v = fmaxf(fmaxf(a00 * aa + bb, a01 * aa + bb),
                            fmaxf(a10 * aa + bb, a11 * aa + bb));
            ub[c] = f2bfu(fmaxf(v, 0.f));
        }
        uint2 pk;
        pk.x = (unsigned)ub[0] | ((unsigned)ub[1] << 16);
        pk.y = (unsigned)ub[2] | ((unsigned)ub[3] << 16);
        int blk = (ocg >> 1) ^ ((px + 1) & 7);   // XOR swizzle by padded column
        *(uint2*)&xs2[((((py + 1) * 16) + (px + 1)) * 8 + blk) * 8 + (ocg & 1) * 4] = pk;
    }
    __syncthreads();
    // xt is DEAD; u3 becomes xs3. Zero only the halo (row 0 cols 0..7, col 0 rows 1..7).
    for (int i = t; i < 960; i += 512) {     // 15 pos x 64 u32
        int pos = i >> 6, w = i & 63;
        int yy = (pos < 8) ? 0 : pos - 7;
        int xx = (pos < 8) ? pos : 0;
        ((unsigned*)xs3)[(yy * 8 + xx) * 64 + w] = 0u;
    }

    // ---- stage B: conv2 (64->128) via MFMA + BN + ReLU + pool -> xs3 (two passes of 7 nt) ----
    int lane = t & 63, wid = t >> 6;         // wid 0..7, one 16-oc tile per wave
    int quad = lane >> 4, n16 = lane & 15;
    int dy = n16 >> 3, lx = n16 & 7;

    {
        int m = lx >> 1;
        bool keep = (dy == 0) && ((lx & 1) == 0);
        int oc0 = wid * 16 + quad * 4;
        float2 abv[4];
#pragma unroll
        for (int r = 0; r < 4; ++r) abv[r] = ab2[oc0 + r];

#pragma unroll 1
        for (int pp = 0; pp < 2; ++pp) {
            f32x4 acc[7];
            f32x4 z = {0.f, 0.f, 0.f, 0.f};
#pragma unroll
            for (int i = 0; i < 7; ++i) acc[i] = z;

#pragma unroll 1
            for (int kykx = 0; kykx < 9; ++kykx) {
                int ky = kykx / 3, kx = kykx - 3 * ky;
                int dyky = dy + ky;
                int xc0 = lx + kx;                       // padded col, cb=0
                int xc1 = xc0 + 8; if (xc1 > 15) xc1 = 15;  // lanes lx>=6 discarded later
#pragma unroll
                for (int kk = 0; kk < 2; ++kk) {
                    s16x8 A = *(const s16x8*)(wT2 + ((kykx * 128 + wid * 16 + n16) * 64 + kk * 32 + quad * 8));
                    int bi = kk * 4 + quad;
#pragma unroll
                    for (int i = 0; i < 7; ++i) {
                        int nt = pp * 7 + i;
                        int ry = nt >> 1, cb = nt & 1;
                        int y_in = 2 * ry + dyky;
                        int x_in = cb ? xc1 : xc0;
                        int blk = bi ^ (x_in & 7);
                        s16x8 B = *(const s16x8*)&xs2[((y_in * 16 + x_in) * 8 + blk) * 8];
                        acc[i] = __builtin_amdgcn_mfma_f32_16x16x32_bf16(A, B, acc[i], 0, 0, 0);
                    }
                }
            }

            // epilogue for this pass: affine -> pool (shfl 1,8) -> ReLU -> xs3 (swizzled)
#pragma unroll
            for (int i = 0; i < 7; ++i) {
                int nt = pp * 7 + i;
                int ry = nt >> 1, cb = nt & 1;
                int xp = cb * 4 + m;
                float pv[4];
#pragma unroll
                for (int r = 0; r < 4; ++r) {
                    float v = acc[i][r] * abv[r].x + abv[r].y;
                    v = fmaxf(v, __shfl_xor(v, 1));
                    v = fmaxf(v, __shfl_xor(v, 8));
                    pv[r] = fmaxf(v, 0.f);
                }
                if (keep && xp < 7) {
                    uint2 pk;
                    pk.x = (unsigned)f2bfu(pv[0]) | ((unsigned)f2bfu(pv[1]) << 16);
                    pk.y = (unsigned)f2bfu(pv[2]) | ((unsigned)f2bfu(pv[3]) << 16);
                    int blk3 = (oc0 >> 3) ^ (((xp + 1) & 7) << 1);
                    *(uint2*)&xs3[(((ry + 1) * 8 + (xp + 1)) * 16 + blk3) * 8 + (oc0 & 7)] = pk;
                }
            }
        }
    }
    __syncthreads();

    // ---- stage C: conv3 (128->256) via MFMA + BN + ReLU + pool + fc1[row1] dot ----
    f32x4 acc[2][3];                         // 2 oc-tiles per wave (8 waves x 2 = 16 tiles = 256 oc)
    f32x4 z = {0.f, 0.f, 0.f, 0.f};
#pragma unroll
    for (int ml = 0; ml < 2; ++ml)
#pragma unroll
        for (int nt = 0; nt < 3; ++nt) acc[ml][nt] = z;

#pragma unroll 1
    for (int kykx = 0; kykx < 9; ++kykx) {
        int ky = kykx / 3, kx = kykx - 3 * ky;
        int dyky = dy + ky;
        int x_in = lx + kx; if (x_in > 7) x_in = 7;   // lanes lx>=6 discarded later
#pragma unroll
        for (int kk = 0; kk < 4; ++kk) {
            s16x8 A[2];
#pragma unroll
            for (int ml = 0; ml < 2; ++ml)
                A[ml] = *(const s16x8*)(wT3 + ((kykx * 256 + (wid * 2 + ml) * 16 + n16) * 128 + kk * 32 + quad * 8));
            int bi = kk * 4 + quad;
            int blk = bi ^ ((x_in & 7) << 1);
#pragma unroll
            for (int nt = 0; nt < 3; ++nt) {
                int y_in = 2 * nt + dyky;
                s16x8 B = *(const s16x8*)&xs3[((y_in * 8 + x_in) * 16 + blk) * 8];
#pragma unroll
                for (int ml = 0; ml < 2; ++ml)
                    acc[ml][nt] = __builtin_amdgcn_mfma_f32_16x16x32_bf16(A[ml], B, acc[ml][nt], 0, 0, 0);
            }
        }
    }
    __syncthreads();                         // all xs3 reads done -> u3 reusable as red

    // epilogue: affine -> pool -> relu -> dot with fc1_w row 1
    float vacc = 0.f;
    int m = lx >> 1;
    bool keep = (dy == 0) && ((lx & 1) == 0) && (m < 3);
    const float* fc1w1 = fc1w + 2304;        // row 1 (only row that matters)
#pragma unroll
    for (int ml = 0; ml < 2; ++ml) {
        int oc0 = (wid * 2 + ml) * 16 + quad * 4;
        float2 abv[4];
#pragma unroll
        for (int r = 0; r < 4; ++r) abv[r] = ab3[oc0 + r];
#pragma unroll
        for (int nt = 0; nt < 3; ++nt) {
#pragma unroll
            for (int r = 0; r < 4; ++r) {
                float v = acc[ml][nt][r] * abv[r].x + abv[r].y;
                v = fmaxf(v, __shfl_xor(v, 1));
                v = fmaxf(v, __shfl_xor(v, 8));
                v = fmaxf(v, 0.f);
                if (keep) vacc += v * fc1w1[(oc0 + r) * 9 + nt * 3 + m];
            }
        }
    }
#pragma unroll
    for (int s = 1; s < 64; s <<= 1) vacc += __shfl_xor(vacc, s);
    if (lane == 0) red[wid] = vacc;
    __syncthreads();
    if (t == 0) {
        float v = red[0] + red[1] + red[2] + red[3]
                + red[4] + red[5] + red[6] + red[7] + qc[5];
        // quantum circuit closed form: <Z0 Z1> = cos(h[:,1]) * cos(qp[1])
        float q = cosf(v) * qc[4];
        float l0 = q * qc[0] + qc[2];
        float l1 = q * qc[1] + qc[3];
        float mx = fmaxf(l0, l1);
        float lse = mx + logf(__expf(l0 - mx) + __expf(l1 - mx));
        out[b * 2 + 0] = l0 - lse;
        out[b * 2 + 1] = l1 - lse;
    }
}

extern "C" void kernel_launch(void* const* d_in, const int* in_sizes, int n_in,
                              void* d_out, int out_size, void* d_ws, size_t ws_size,
                              hipStream_t stream)
{
    const float* x    = (const float*)d_in[0];
    const float* c1w  = (const float*)d_in[1];
    const float* c1b  = (const float*)d_in[2];
    const float* c2w  = (const float*)d_in[3];
    const float* c2b  = (const float*)d_in[4];
    const float* c3w  = (const float*)d_in[5];
    const float* c3b  = (const float*)d_in[6];
    const float* g1   = (const float*)d_in[7];
    const float* b1   = (const float*)d_in[8];
    const float* m1   = (const float*)d_in[9];
    const float* v1   = (const float*)d_in[10];
    const float* g2   = (const float*)d_in[11];
    const float* b2   = (const float*)d_in[12];
    const float* m2   = (const float*)d_in[13];
    const float* v2   = (const float*)d_in[14];
    const float* g3   = (const float*)d_in[15];
    const float* b3   = (const float*)d_in[16];
    const float* m3   = (const float*)d_in[17];
    const float* v3   = (const float*)d_in[18];
    const float* fc1w = (const float*)d_in[19];
    const float* fc1b = (const float*)d_in[20];
    const float* qp   = (const float*)d_in[21];
    const float* fc2w = (const float*)d_in[22];
    const float* fc2b = (const float*)d_in[23];
    const float* fc3w = (const float*)d_in[24];
    const float* fc3b = (const float*)d_in[25];
    float* out = (float*)d_out;
    char* ws = (char*)d_ws;

    short*  wT2 = (short*)(ws + OFF_W2);
    short*  wT3 = (short*)(ws + OFF_W3);
    float2* ab1 = (float2*)(ws + OFF_AB1);
    float2* ab2 = (float2*)(ws + OFF_AB2);
    float2* ab3 = (float2*)(ws + OFF_AB3);
    float*  qc  = (float*)(ws + OFF_Q);

    int B = in_sizes[0] / 784;               // 8192

    prep_k<<<1152, 256, 0, stream>>>(c2w, c3w, c1b, g1, b1, m1, v1,
                                     c2b, g2, b2, m2, v2, c3b, g3, b3, m3, v3,
                                     fc1b, qp, fc2w, fc2b, fc3w, fc3b,
                                     wT2, wT3, ab1, ab2, ab3, qc);
    fused_k<<<B, 512, 0, stream>>>(x, c1w, ab1, ab2, ab3, wT2, wT3, fc1w, qc, out);
}

// Round 12
// 928.924 us; speedup vs baseline: 2.5569x; 1.0804x over previous
//
#include <hip/hip_runtime.h>
#include <hip/hip_bf16.h>
#include <math.h>

typedef float f32x4 __attribute__((ext_vector_type(4)));
typedef short s16x8 __attribute__((ext_vector_type(8)));

// ---- workspace layout (bytes) ---- total < 1 MB
static const long long OFF_W2  = 0LL;        // bf16 [9][128][64]  = 147,456 B
static const long long OFF_W3  = 147456LL;   // bf16 [9][256][128] = 589,824 B
static const long long OFF_AB1 = 737280LL;   // float2 [64]
static const long long OFF_AB2 = 737792LL;   // float2 [128]
static const long long OFF_AB3 = 738816LL;   // float2 [256]
static const long long OFF_Q   = 740864LL;   // float  [8]: A0,A1,C0,C1,cos(qp1),fc1b1

__device__ inline unsigned short f2bfu(float f) {
    __hip_bfloat16 h = __float2bfloat16(f);
    unsigned short u;
    __builtin_memcpy(&u, &h, 2);
    return u;
}

// ---------------- prep: weight transpose to [kykx][oc][ic] bf16 + BN folding + fc fold ----------------
__global__ __launch_bounds__(256) void prep_k(
    const float* __restrict__ c2w, const float* __restrict__ c3w,
    const float* __restrict__ c1b, const float* __restrict__ g1, const float* __restrict__ b1,
    const float* __restrict__ m1, const float* __restrict__ v1,
    const float* __restrict__ c2b, const float* __restrict__ g2, const float* __restrict__ b2,
    const float* __restrict__ m2, const float* __restrict__ v2,
    const float* __restrict__ c3b, const float* __restrict__ g3, const float* __restrict__ b3,
    const float* __restrict__ m3, const float* __restrict__ v3,
    const float* __restrict__ fc1b, const float* __restrict__ qp,
    const float* __restrict__ fc2w, const float* __restrict__ fc2b,
    const float* __restrict__ fc3w, const float* __restrict__ fc3b,
    short* __restrict__ wT2, short* __restrict__ wT3,
    float2* __restrict__ ab1, float2* __restrict__ ab2, float2* __restrict__ ab3,
    float* __restrict__ qc)
{
    int tid = blockIdx.x * 256 + threadIdx.x;
    if (tid < 73728) {                       // 9*128*64
        int ic = tid & 63, oc = (tid >> 6) & 127, k = tid >> 13;
        wT2[tid] = (short)f2bfu(c2w[(oc * 64 + ic) * 9 + k]);
    }
    if (tid < 294912) {                      // 9*256*128
        int ic = tid & 127, oc = (tid >> 7) & 255, k = tid >> 15;
        wT3[tid] = (short)f2bfu(c3w[(oc * 128 + ic) * 9 + k]);
    }
    if (tid < 64) {
        float s = g1[tid] / sqrtf(v1[tid] + 1e-5f);
        ab1[tid] = make_float2(s, (c1b[tid] - m1[tid]) * s + b1[tid]);
    } else if (tid < 192) {
        int c = tid - 64;
        float s = g2[c] / sqrtf(v2[c] + 1e-5f);
        ab2[c] = make_float2(s, (c2b[c] - m2[c]) * s + b2[c]);
    } else if (tid < 448) {
        int c = tid - 192;
        float s = g3[c] / sqrtf(v3[c] + 1e-5f);
        ab3[c] = make_float2(s, (c3b[c] - m3[c]) * s + b3[c]);
    } else if (tid == 448) {
        float A0 = 0.f, A1 = 0.f, B0 = 0.f, B1 = 0.f;
        for (int k = 0; k < 128; ++k) {
            float f2 = fc2w[k], fb = fc2b[k];
            A0 += fc3w[k] * f2;        B0 += fc3w[k] * fb;
            A1 += fc3w[128 + k] * f2;  B1 += fc3w[128 + k] * fb;
        }
        qc[0] = A0; qc[1] = A1;
        qc[2] = B0 + fc3b[0]; qc[3] = B1 + fc3b[1];
        qc[4] = cosf(qp[1]);  qc[5] = fc1b[1];
    }
}

// ---------------- fused: R4 skeleton + low-pressure stage A ----------------
// EXACT R4 structure (48 KB LDS union, (512,6) -> 3 blocks/CU, single-pass conv2 acc[14],
// R4 = 935us session best) with ONE change: stage A split into 32 oc-groups x 2 oc
// (wr[2][9]=18 regs vs wr[4][9]=36). Stage-A live set ~70 -> ~46 regs, giving the allocator
// slack to fit conv2's ~82-reg peak under the 85-reg 6-wave cap WITHOUT R4's 177 MB spill.
// Cost: patch reads double (98 -> 196 ds_read_b32/thread, ~+4.5K cyc/block LDS port).
// Single-variable test: was R4's spill the remaining tax, or is 935 a structural plateau?
__global__ __launch_bounds__(512, 6) void fused_k(
    const float* __restrict__ x, const float* __restrict__ c1w,
    const float2* __restrict__ ab1, const float2* __restrict__ ab2,
    const float2* __restrict__ ab3,
    const short* __restrict__ wT2, const short* __restrict__ wT3,
    const float* __restrict__ fc1w, const float* __restrict__ qc,
    float* __restrict__ out)
{
    __shared__ short xs2[16 * 16 * 64];      // conv2 input tile [y][x][8 blk][8 ic], swizzled (32 KB)
    __shared__ short u3[8 * 8 * 128];        // 16 KB UNION: stage-A xt / conv3 xs3 / final red

    float (*xt)[32] = (float (*)[32])u3;     // padded 28x28 input at [1..28][1..28]
    short* xs3 = u3;                         // conv3 input tile [y][x][16 blk][8 ic], swizzled
    float* red = (float*)u3;                 // 8 floats, valid only after post-conv3 barrier

    int b = blockIdx.x, t = threadIdx.x;

    // ---- zero-init (xs2 fully; xt incl. borders) ----
    for (int i = t; i < 8192; i += 512) ((unsigned*)xs2)[i] = 0u;
    for (int i = t; i < 960;  i += 512) ((unsigned*)u3)[i] = 0u;
    __syncthreads();

    // ---- stage A: load input, conv1 (VALU fp32) + BN + ReLU + 2x2 pool -> xs2 ----
    for (int i = t; i < 784; i += 512) xt[i / 28 + 1][i % 28 + 1] = x[b * 784 + i];

    int ocg2 = t & 31;                       // 32 groups of 2 output channels
    float wr[2][9];
    float2 abr[2];
#pragma unroll
    for (int c = 0; c < 2; ++c) {
#pragma unroll
        for (int k = 0; k < 9; ++k) wr[c][k] = c1w[(ocg2 * 2 + c) * 9 + k];
        abr[c] = ab1[ocg2 * 2 + c];
    }
    __syncthreads();

    int posb = t >> 5;                       // 0..15
    for (int p = posb; p < 196; p += 16) {
        int py = p / 14, px = p % 14;
        int y0 = 2 * py, x0 = 2 * px;
        float patch[4][4];
#pragma unroll
        for (int i = 0; i < 4; ++i)
#pragma unroll
            for (int j = 0; j < 4; ++j) patch[i][j] = xt[y0 + i][x0 + j];

        unsigned short ub[2];
#pragma unroll
        for (int c = 0; c < 2; ++c) {
            float a00 = 0.f, a01 = 0.f, a10 = 0.f, a11 = 0.f;
#pragma unroll
            for (int ky = 0; ky < 3; ++ky)
#pragma unroll
                for (int kx = 0; kx < 3; ++kx) {
                    float wv = wr[c][ky * 3 + kx];
                    a00 += patch[ky + 0][kx + 0] * wv;
                    a01 += patch[ky + 0][kx + 1] * wv;
                    a10 += patch[ky + 1][kx + 0] * wv;
                    a11 += patch[ky + 1][kx + 1] * wv;
                }
            float aa = abr[c].x, bb = abr[c].y;
            float v = fmaxf(fmaxf(a00 * aa + bb, a01 * aa + bb),
                            fmaxf(a10 * aa + bb, a11 * aa + bb));
            ub[c] = f2bfu(fmaxf(v, 0.f));
        }
        unsigned pk = (unsigned)ub[0] | ((unsigned)ub[1] << 16);
        int oc0 = ocg2 * 2;                  // ic-group g = oc0>>3 = ocg2>>2; within-block = oc0&7
        int blk = (ocg2 >> 2) ^ ((px + 1) & 7);   // XOR swizzle by padded column
        *(unsigned*)&xs2[((((py + 1) * 16) + (px + 1)) * 8 + blk) * 8 + (oc0 & 7)] = pk;
    }
    __syncthreads();
    // xt is DEAD; u3 becomes xs3. Zero only the halo (row 0 cols 0..7, col 0 rows 1..7).
    for (int i = t; i < 960; i += 512) {     // 15 pos x 64 u32
        int pos = i >> 6, w = i & 63;
        int yy = (pos < 8) ? 0 : pos - 7;
        int xx = (pos < 8) ? pos : 0;
        ((unsigned*)xs3)[(yy * 8 + xx) * 64 + w] = 0u;
    }

    // ---- stage B: conv2 (64->128) via MFMA + BN + ReLU + pool -> xs3 (single pass, acc[14]) ----
    int lane = t & 63, wid = t >> 6;         // wid 0..7, one 16-oc tile per wave
    int quad = lane >> 4, n16 = lane & 15;
    int dy = n16 >> 3, lx = n16 & 7;

    {
        f32x4 acc[14];
        f32x4 z = {0.f, 0.f, 0.f, 0.f};
#pragma unroll
        for (int nt = 0; nt < 14; ++nt) acc[nt] = z;

#pragma unroll 1
        for (int kykx = 0; kykx < 9; ++kykx) {
            int ky = kykx / 3, kx = kykx - 3 * ky;
            int dyky = dy + ky;
            int xc0 = lx + kx;                       // padded col, cb=0
            int xc1 = xc0 + 8; if (xc1 > 15) xc1 = 15;  // cb=1; lanes lx>=6 discarded later
#pragma unroll
            for (int kk = 0; kk < 2; ++kk) {
                s16x8 A = *(const s16x8*)(wT2 + ((kykx * 128 + wid * 16 + n16) * 64 + kk * 32 + quad * 8));
                int bi = kk * 4 + quad;
#pragma unroll
                for (int nt = 0; nt < 14; ++nt) {
                    int ry = nt >> 1, cb = nt & 1;
                    int y_in = 2 * ry + dyky;
                    int x_in = cb ? xc1 : xc0;
                    int blk = bi ^ (x_in & 7);
                    s16x8 B = *(const s16x8*)&xs2[((y_in * 16 + x_in) * 8 + blk) * 8];
                    acc[nt] = __builtin_amdgcn_mfma_f32_16x16x32_bf16(A, B, acc[nt], 0, 0, 0);
                }
            }
        }

        // epilogue: affine -> pool (shfl 1,8) -> ReLU -> store into xs3 (swizzled)
        int m = lx >> 1;
        bool keep = (dy == 0) && ((lx & 1) == 0);
        int oc0 = wid * 16 + quad * 4;
        float2 abv[4];
#pragma unroll
        for (int r = 0; r < 4; ++r) abv[r] = ab2[oc0 + r];
#pragma unroll
        for (int nt = 0; nt < 14; ++nt) {
            int ry = nt >> 1, cb = nt & 1;
            int xp = cb * 4 + m;
            float pv[4];
#pragma unroll
            for (int r = 0; r < 4; ++r) {
                float v = acc[nt][r] * abv[r].x + abv[r].y;
                v = fmaxf(v, __shfl_xor(v, 1));
                v = fmaxf(v, __shfl_xor(v, 8));
                pv[r] = fmaxf(v, 0.f);
            }
            if (keep && xp < 7) {
                uint2 pk;
                pk.x = (unsigned)f2bfu(pv[0]) | ((unsigned)f2bfu(pv[1]) << 16);
                pk.y = (unsigned)f2bfu(pv[2]) | ((unsigned)f2bfu(pv[3]) << 16);
                int blk3 = (oc0 >> 3) ^ (((xp + 1) & 7) << 1);
                *(uint2*)&xs3[(((ry + 1) * 8 + (xp + 1)) * 16 + blk3) * 8 + (oc0 & 7)] = pk;
            }
        }
    }
    __syncthreads();

    // ---- stage C: conv3 (128->256) via MFMA + BN + ReLU + pool + fc1[row1] dot ----
    f32x4 acc[2][3];                         // 2 oc-tiles per wave (8 waves x 2 = 16 tiles = 256 oc)
    f32x4 z = {0.f, 0.f, 0.f, 0.f};
#pragma unroll
    for (int ml = 0; ml < 2; ++ml)
#pragma unroll
        for (int nt = 0; nt < 3; ++nt) acc[ml][nt] = z;

#pragma unroll 1
    for (int kykx = 0; kykx < 9; ++kykx) {
        int ky = kykx / 3, kx = kykx - 3 * ky;
        int dyky = dy + ky;
        int x_in = lx + kx; if (x_in > 7) x_in = 7;   // lanes lx>=6 discarded later
#pragma unroll
        for (int kk = 0; kk < 4; ++kk) {
            s16x8 A[2];
#pragma unroll
            for (int ml = 0; ml < 2; ++ml)
                A[ml] = *(const s16x8*)(wT3 + ((kykx * 256 + (wid * 2 + ml) * 16 + n16) * 128 + kk * 32 + quad * 8));
            int bi = kk * 4 + quad;
            int blk = bi ^ ((x_in & 7) << 1);
#pragma unroll
            for (int nt = 0; nt < 3; ++nt) {
                int y_in = 2 * nt + dyky;
                s16x8 B = *(const s16x8*)&xs3[((y_in * 8 + x_in) * 16 + blk) * 8];
#pragma unroll
                for (int ml = 0; ml < 2; ++ml)
                    acc[ml][nt] = __builtin_amdgcn_mfma_f32_16x16x32_bf16(A[ml], B, acc[ml][nt], 0, 0, 0);
            }
        }
    }
    __syncthreads();                         // all xs3 reads done -> u3 reusable as red

    // epilogue: affine -> pool -> relu -> dot with fc1_w row 1
    float vacc = 0.f;
    int m = lx >> 1;
    bool keep = (dy == 0) && ((lx & 1) == 0) && (m < 3);
    const float* fc1w1 = fc1w + 2304;        // row 1 (only row that matters)
#pragma unroll
    for (int ml = 0; ml < 2; ++ml) {
        int oc0 = (wid * 2 + ml) * 16 + quad * 4;
        float2 abv[4];
#pragma unroll
        for (int r = 0; r < 4; ++r) abv[r] = ab3[oc0 + r];
#pragma unroll
        for (int nt = 0; nt < 3; ++nt) {
#pragma unroll
            for (int r = 0; r < 4; ++r) {
                float v = acc[ml][nt][r] * abv[r].x + abv[r].y;
                v = fmaxf(v, __shfl_xor(v, 1));
                v = fmaxf(v, __shfl_xor(v, 8));
                v = fmaxf(v, 0.f);
                if (keep) vacc += v * fc1w1[(oc0 + r) * 9 + nt * 3 + m];
            }
        }
    }
#pragma unroll
    for (int s = 1; s < 64; s <<= 1) vacc += __shfl_xor(vacc, s);
    if (lane == 0) red[wid] = vacc;
    __syncthreads();
    if (t == 0) {
        float v = red[0] + red[1] + red[2] + red[3]
                + red[4] + red[5] + red[6] + red[7] + qc[5];
        // quantum circuit closed form: <Z0 Z1> = cos(h[:,1]) * cos(qp[1])
        float q = cosf(v) * qc[4];
        float l0 = q * qc[0] + qc[2];
        float l1 = q * qc[1] + qc[3];
        float mx = fmaxf(l0, l1);
        float lse = mx + logf(__expf(l0 - mx) + __expf(l1 - mx));
        out[b * 2 + 0] = l0 - lse;
        out[b * 2 + 1] = l1 - lse;
    }
}

extern "C" void kernel_launch(void* const* d_in, const int* in_sizes, int n_in,
                              void* d_out, int out_size, void* d_ws, size_t ws_size,
                              hipStream_t stream)
{
    const float* x    = (const float*)d_in[0];
    const float* c1w  = (const float*)d_in[1];
    const float* c1b  = (const float*)d_in[2];
    const float* c2w  = (const float*)d_in[3];
    const float* c2b  = (const float*)d_in[4];
    const float* c3w  = (const float*)d_in[5];
    const float* c3b  = (const float*)d_in[6];
    const float* g1   = (const float*)d_in[7];
    const float* b1   = (const float*)d_in[8];
    const float* m1   = (const float*)d_in[9];
    const float* v1   = (const float*)d_in[10];
    const float* g2   = (const float*)d_in[11];
    const float* b2   = (const float*)d_in[12];
    const float* m2   = (const float*)d_in[13];
    const float* v2   = (const float*)d_in[14];
    const float* g3   = (const float*)d_in[15];
    const float* b3   = (const float*)d_in[16];
    const float* m3   = (const float*)d_in[17];
    const float* v3   = (const float*)d_in[18];
    const float* fc1w = (const float*)d_in[19];
    const float* fc1b = (const float*)d_in[20];
    const float* qp   = (const float*)d_in[21];
    const float* fc2w = (const float*)d_in[22];
    const float* fc2b = (const float*)d_in[23];
    const float* fc3w = (const float*)d_in[24];
    const float* fc3b = (const float*)d_in[25];
    float* out = (float*)d_out;
    char* ws = (char*)d_ws;

    short*  wT2 = (short*)(ws + OFF_W2);
    short*  wT3 = (short*)(ws + OFF_W3);
    float2* ab1 = (float2*)(ws + OFF_AB1);
    float2* ab2 = (float2*)(ws + OFF_AB2);
    float2* ab3 = (float2*)(ws + OFF_AB3);
    float*  qc  = (float*)(ws + OFF_Q);

    int B = in_sizes[0] / 784;               // 8192

    prep_k<<<1152, 256, 0, stream>>>(c2w, c3w, c1b, g1, b1, m1, v1,
                                     c2b, g2, b2, m2, v2, c3b, g3, b3, m3, v3,
                                     fc1b, qp, fc2w, fc2b, fc3w, fc3b,
                                     wT2, wT3, ab1, ab2, ab3, qc);
    fused_k<<<B, 512, 0, stream>>>(x, c1w, ab1, ab2, ab3, wT2, wT3, fc1w, qc, out);
}